// Round 7
// baseline (310.422 us; speedup 1.0000x reference)
//
#include <hip/hip_runtime.h>
#include <stdint.h>

#define NROW    8192
#define CDIM    256
#define NCODE   16384
#define MARGINF 1.6e-4f

typedef short short8 __attribute__((ext_vector_type(8)));
typedef float floatx4 __attribute__((ext_vector_type(4)));
typedef _Float16 half2v __attribute__((ext_vector_type(2)));

__device__ inline ushort f2bf(float f) {
    unsigned u = __builtin_bit_cast(unsigned, f);
    unsigned r = (u + 0x7fffu + ((u >> 16) & 1u)) >> 16;
    return (ushort)r;
}
__device__ inline unsigned fsort(float v) {
    unsigned u = __builtin_bit_cast(unsigned, v);
    return (u >> 31) ? ~u : (u | 0x80000000u);
}

__device__ inline void gl_lds16(const ushort* g, ushort* lds) {
    __builtin_amdgcn_global_load_lds(
        (const __attribute__((address_space(1))) unsigned int*)(g),
        (__attribute__((address_space(3))) unsigned int*)(lds),
        16, 0, 0);
}

// ---------------------------------------------------------------------------
// x (B,C,H,W) fp32 -> xf32[n][c] and xbf[n][c] (bf16), n = b*1024 + hw
// ---------------------------------------------------------------------------
__global__ __launch_bounds__(256) void prep_x(const float* __restrict__ x,
                                              float* __restrict__ xf32,
                                              ushort* __restrict__ xbf) {
    __shared__ float tile[32][33];
    const int b = blockIdx.x, ht = blockIdx.y, ct = blockIdx.z;
    const int t = threadIdx.x;
    const int hw0 = ht * 32, c0 = ct * 32;
    {
        const int cc = t >> 5, hh = t & 31;
        #pragma unroll
        for (int i = 0; i < 4; ++i) {
            int cl = cc + i * 8;
            tile[cl][hh] = x[((size_t)(b * 256 + c0 + cl) << 10) + hw0 + hh];
        }
    }
    __syncthreads();
    {
        const int col = t & 31, row = t >> 5;
        #pragma unroll
        for (int i = 0; i < 4; ++i) {
            int r = row + i * 8;
            float v = tile[col][r];
            size_t o = ((size_t)(b * 1024 + hw0 + r) << 8) + c0 + col;
            xf32[o] = v;
            xbf[o] = f2bf(v);
        }
    }
}

// ---------------------------------------------------------------------------
// 2 threads per code j (one per 128-half): bf16 copy + exact np pairwise S2
// ---------------------------------------------------------------------------
__global__ __launch_bounds__(256) void prep_w2(const float* __restrict__ w,
                                               ushort* __restrict__ wbf,
                                               float* __restrict__ S2a) {
#pragma clang fp contract(off)
    const int gt = blockIdx.x * 256 + threadIdx.x;
    const int j = gt >> 1, h = gt & 1;
    const float* a = w + ((size_t)j << 8) + h * 128;
    ushort* orow = wbf + ((size_t)j << 8) + h * 128;
    float r8[8];
    #pragma unroll
    for (int l = 0; l < 8; ++l) { float v = a[l]; r8[l] = v * v; }
    for (int i = 8; i < 128; i += 8) {
        #pragma unroll
        for (int l = 0; l < 8; ++l) { float v = a[i + l]; r8[l] = r8[l] + v * v; }
    }
    float hs = ((r8[0] + r8[1]) + (r8[2] + r8[3])) + ((r8[4] + r8[5]) + (r8[6] + r8[7]));
    float other = __shfl_xor(hs, 1);
    if (h == 0) S2a[j] = hs + other;   // fl(hs0 + hs1) — np order
    for (int i = 0; i < 128; i += 8) {
        ushort u8[8];
        #pragma unroll
        for (int l = 0; l < 8; ++l) u8[l] = f2bf(a[i + l]);
        *(ushort4*)(orow + i)     = make_ushort4(u8[0], u8[1], u8[2], u8[3]);
        *(ushort4*)(orow + i + 4) = make_ushort4(u8[4], u8[5], u8[6], u8[7]);
    }
}

// ---------------------------------------------------------------------------
// bf16 MFMA GEMM with CODES on M, QUERIES on N (cheap in-lane epilogue).
// global_load_lds staging, XOR-swizzled LDS layout.
// Emits per (query row, 16-code block) min approx score as fp16:
//   bm16[n][1024], 16-block id jb = blockIdx.y*8 + wr*4 + mi.
// score = S2[j] - 2 * x.w  (S1 omitted: constant per row)
// ---------------------------------------------------------------------------
__global__ __launch_bounds__(256) void gemm_min(const ushort* __restrict__ Wb,
                                                const ushort* __restrict__ Xb,
                                                const float* __restrict__ S2a,
                                                ushort* __restrict__ bm16) {
    __shared__ __attribute__((aligned(16))) ushort As[8192];  // codes  [128][64] swz
    __shared__ __attribute__((aligned(16))) ushort Bs[8192];  // queries[128][64] swz
    __shared__ __attribute__((aligned(16))) ushort stg[128 * 8];

    const int n0 = blockIdx.x * 128;   // query block
    const int j0 = blockIdx.y * 128;   // code block
    const int t  = threadIdx.x;
    const int wv = t >> 6, l = t & 63;
    const int wr = wv >> 1, wc = wv & 1;   // wr: code 64-half, wc: query 64-half
    const int q  = l >> 4, c = l & 15;

    const int lr = l >> 3;
    const int lperm = (l & 7) ^ lr;
    const size_t gA0 = ((size_t)(j0 + wv * 32 + lr) << 8) + lperm * 8;
    const size_t gB0 = ((size_t)(n0 + wv * 32 + lr) << 8) + lperm * 8;
    const int ldsbase = wv * 2048;

    floatx4 acc[4][4];
    #pragma unroll
    for (int mi = 0; mi < 4; ++mi)
        #pragma unroll
        for (int ni = 0; ni < 4; ++ni)
            acc[mi][ni] = (floatx4){0.f, 0.f, 0.f, 0.f};

    for (int kb = 0; kb < 4; ++kb) {
        if (kb) __syncthreads();
        #pragma unroll
        for (int ca = 0; ca < 4; ++ca) {
            gl_lds16(Wb + gA0 + ca * 2048 + kb * 64, As + ldsbase + ca * 512);
            gl_lds16(Xb + gB0 + ca * 2048 + kb * 64, Bs + ldsbase + ca * 512);
        }
        __syncthreads();
        #pragma unroll
        for (int kk = 0; kk < 2; ++kk) {
            short8 af[4], bf[4];
            #pragma unroll
            for (int mi = 0; mi < 4; ++mi) {
                int row = wr * 64 + mi * 16 + c;
                int pos = (kk * 4 + q) ^ (c & 7);
                af[mi] = *(const short8*)&As[row * 64 + pos * 8];
            }
            #pragma unroll
            for (int ni = 0; ni < 4; ++ni) {
                int row = wc * 64 + ni * 16 + c;
                int pos = (kk * 4 + q) ^ (c & 7);
                bf[ni] = *(const short8*)&Bs[row * 64 + pos * 8];
            }
            #pragma unroll
            for (int mi = 0; mi < 4; ++mi)
                #pragma unroll
                for (int ni = 0; ni < 4; ++ni)
                    acc[mi][ni] = __builtin_amdgcn_mfma_f32_16x16x32_bf16(
                        af[mi], bf[ni], acc[mi][ni], 0, 0, 0);
        }
    }

    // Epilogue: D rows = codes (q*4+r), cols = queries (c).
    #pragma unroll
    for (int mi = 0; mi < 4; ++mi) {
        float4 s2 = *(const float4*)&S2a[j0 + wr * 64 + mi * 16 + (q << 2)];
        #pragma unroll
        for (int ni = 0; ni < 4; ++ni) {
            float m0 = fmaf(-2.f, acc[mi][ni][0], s2.x);
            float m1 = fmaf(-2.f, acc[mi][ni][1], s2.y);
            float m2 = fmaf(-2.f, acc[mi][ni][2], s2.z);
            float m3 = fmaf(-2.f, acc[mi][ni][3], s2.w);
            float m = fminf(fminf(m0, m1), fminf(m2, m3));
            m = fminf(m, __shfl_xor(m, 16));
            m = fminf(m, __shfl_xor(m, 32));
            if (q == 0) {
                int qr = wc * 64 + ni * 16 + c;        // query row in block
                stg[qr * 8 + wr * 4 + mi] =
                    __builtin_bit_cast(ushort, (_Float16)m);
            }
        }
    }
    __syncthreads();
    if (t < 128) {
        uint4 v = *(const uint4*)&stg[t * 8];
        *(uint4*)(bm16 + ((size_t)(n0 + t) << 10) + blockIdx.y * 8) = v;
    }
}

// ---------------------------------------------------------------------------
// ONE WAVE PER ROW (4 rows/block, no cross-wave coupling, no hot barriers).
// Lane l owns 16 of the 1024 fp16 block-mins; wave-reduce min; candidate
// blocks within MARGIN listed per-wave; then ONE CANDIDATE CODE PER LANE:
// each active lane streams its w row (64 independent float4 gathers, high
// MLP) and runs the exact np-fp32 sequential-FMA dot from LDS-broadcast x.
// First-index tie-break via u64 key. Loss fused.
// ---------------------------------------------------------------------------
__global__ __launch_bounds__(256) void rescore4(const ushort* __restrict__ bm16,
                                                const float* __restrict__ xf32,
                                                const float* __restrict__ w,
                                                const float* __restrict__ S2a,
                                                int* __restrict__ idxb,
                                                float* __restrict__ xcode,
                                                float* __restrict__ loss) {
#pragma clang fp contract(off)
    __shared__ float xs[4][256];
    __shared__ short list[4][128];
    __shared__ int ncand[4];

    const int t = threadIdx.x, wv = t >> 6, l = t & 63;
    const int n = blockIdx.x * 4 + wv;
    if (l == 0) ncand[wv] = 0;

    // stage xrow (coalesced float4/lane)
    const float4 xv = *(const float4*)&xf32[((size_t)n << 8) + l * 4];
    *(float4*)&xs[wv][l * 4] = xv;

    // bm16 row: lane l covers blocks l*16 .. l*16+15 (32 B/lane, coalesced)
    const uint4* bp = (const uint4*)(bm16 + ((size_t)n << 10) + l * 16);
    const uint4 b0 = bp[0], b1 = bp[1];
    float vals[16];
    {
        unsigned uu[8] = {b0.x, b0.y, b0.z, b0.w, b1.x, b1.y, b1.z, b1.w};
        #pragma unroll
        for (int i = 0; i < 8; ++i) {
            half2v h = __builtin_bit_cast(half2v, uu[i]);
            vals[2 * i]     = (float)h[0];
            vals[2 * i + 1] = (float)h[1];
        }
    }
    float vmin = vals[0];
    #pragma unroll
    for (int i = 1; i < 16; ++i) vmin = fminf(vmin, vals[i]);
    #pragma unroll
    for (int off = 1; off <= 32; off <<= 1) vmin = fminf(vmin, __shfl_xor(vmin, off));
    const float thr = vmin + MARGINF;
    #pragma unroll
    for (int i = 0; i < 16; ++i)
        if (vals[i] <= thr) {
            int p = atomicAdd(&ncand[wv], 1);
            if (p < 128) list[wv][p] = (short)(l * 16 + i);
        }

    // exact np pairwise S1: lanes 0..15 (half h = l>>3, accumulator a = l&7)
    float racc = 0.f;
    if (l < 16) {
        const float* a_ = &xs[wv][(l >> 3) * 128];
        const int ai = l & 7;
        float v = a_[ai];
        racc = v * v;
        for (int i = 8; i < 128; i += 8) { v = a_[i + ai]; racc = racc + v * v; }
    }
    // butterfly reproduces ((r0+r1)+(r2+r3))+((r4+r5)+(r6+r7)), then hs0+hs1
    racc = racc + __shfl_xor(racc, 1);
    racc = racc + __shfl_xor(racc, 2);
    racc = racc + __shfl_xor(racc, 4);
    racc = racc + __shfl_xor(racc, 8);   // lane 0: hs0 + hs1 (np order)
    const float S1n = __shfl(racc, 0);

    // one candidate code per lane
    const int ntot = (ncand[wv] < 128 ? ncand[wv] : 128) * 16;
    unsigned long long best = ~0ull;
    for (int s = l; s < ntot; s += 64) {
        const int j = (int)list[wv][s >> 4] * 16 + (s & 15);
        const float* wr_ = w + ((size_t)j << 8);
        float g = 0.f;
        #pragma unroll 8
        for (int k = 0; k < 256; k += 4) {   // sequential FMA in k-order (BLAS)
            float4 wvv = *(const float4*)(wr_ + k);
            g = fmaf(xs[wv][k],     wvv.x, g);
            g = fmaf(xs[wv][k + 1], wvv.y, g);
            g = fmaf(xs[wv][k + 2], wvv.z, g);
            g = fmaf(xs[wv][k + 3], wvv.w, g);
        }
        float d = (S1n + S2a[j]) - 2.0f * g;
        unsigned long long key = ((unsigned long long)fsort(d) << 32) | (unsigned)j;
        if (key < best) best = key;
    }
    #pragma unroll
    for (int off = 1; off <= 32; off <<= 1) {
        unsigned long long o = __shfl_xor(best, off);
        if (o < best) best = o;
    }
    const int J = (int)(best & 0xffffffffu);
    if (l == 0) {
        idxb[n] = J;
        xcode[n] = (float)J;
    }
    // loss contribution for this row (w[J] is L2-hot)
    const float4 wj = *(const float4*)&w[((size_t)J << 8) + l * 4];
    float d0 = wj.x - xv.x, d1 = wj.y - xv.y, d2 = wj.z - xv.z, d3 = wj.w - xv.w;
    float lacc = (d0 * d0 + d1 * d1) + (d2 * d2 + d3 * d3);
    #pragma unroll
    for (int off = 1; off <= 32; off <<= 1) lacc += __shfl_xor(lacc, off);
    if (l == 0) atomicAdd(loss, lacc * (1.25f / 2097152.0f));
}

// ---------------------------------------------------------------------------
// xq_img gather (loss handled in rescore4)
// ---------------------------------------------------------------------------
__global__ __launch_bounds__(256) void outputs_k(const float* __restrict__ w,
                                                 const int* __restrict__ idxb,
                                                 float* __restrict__ out) {
    const int b = blockIdx.x, hq = blockIdx.y, cs = blockIdx.z;
    const int t = threadIdx.x;
    const int hw = hq * 256 + t;
    const int n = (b << 10) + hw;
    const int id = idxb[n];
    #pragma unroll 4
    for (int ci = 0; ci < 32; ++ci) {
        const int c_ = cs * 32 + ci;
        const size_t oo = ((size_t)((b << 8) + c_) << 10) + hw;
        out[oo] = w[((size_t)id << 8) + c_];
    }
}

// ---------------------------------------------------------------------------
extern "C" void kernel_launch(void* const* d_in, const int* in_sizes, int n_in,
                              void* d_out, int out_size, void* d_ws, size_t ws_size,
                              hipStream_t stream) {
    const float* x = (const float*)d_in[0];
    const float* w = (const float*)d_in[1];
    float* out = (float*)d_out;

    char* ws = (char*)d_ws;
    const size_t MB = 1024u * 1024u;
    ushort* xbf   = (ushort*)(ws);                   //  4 MiB
    float*  xf32  = (float*) (ws + 4 * MB);          //  8 MiB
    ushort* wbf   = (ushort*)(ws + 12 * MB);         //  8 MiB
    float*  S2a   = (float*) (ws + 20 * MB);         // 64 KiB
    ushort* bm16  = (ushort*)(ws + 21 * MB);         // 16 MiB
    int*    idxb  = (int*)   (ws + 37 * MB);         // 32 KiB

    float* loss_ptr  = out + 2097152;
    float* xcode_ptr = out + 2097153;

    hipMemsetAsync((void*)loss_ptr, 0, 4, stream);

    prep_x  <<<dim3(8, 32, 8), 256, 0, stream>>>(x, xf32, xbf);
    prep_w2 <<<dim3(128),      256, 0, stream>>>(w, wbf, S2a);
    gemm_min<<<dim3(64, 128),  256, 0, stream>>>(wbf, xbf, S2a, bm16);
    rescore4<<<dim3(2048),     256, 0, stream>>>(bm16, xf32, w, S2a, idxb,
                                                 xcode_ptr, loss_ptr);
    outputs_k<<<dim3(8, 4, 8), 256, 0, stream>>>(w, idxb, out);
}

// Round 8
// 305.126 us; speedup vs baseline: 1.0174x; 1.0174x over previous
//
#include <hip/hip_runtime.h>
#include <stdint.h>

#define NROW    8192
#define CDIM    256
#define NCODE   16384
#define MARGINF 6.0e-5f

typedef short short8 __attribute__((ext_vector_type(8)));
typedef float floatx4 __attribute__((ext_vector_type(4)));
typedef _Float16 half2v __attribute__((ext_vector_type(2)));

__device__ inline ushort f2bf(float f) {
    unsigned u = __builtin_bit_cast(unsigned, f);
    unsigned r = (u + 0x7fffu + ((u >> 16) & 1u)) >> 16;
    return (ushort)r;
}
__device__ inline unsigned fsort(float v) {
    unsigned u = __builtin_bit_cast(unsigned, v);
    return (u >> 31) ? ~u : (u | 0x80000000u);
}

__device__ inline void gl_lds16(const ushort* g, ushort* lds) {
    __builtin_amdgcn_global_load_lds(
        (const __attribute__((address_space(1))) unsigned int*)(g),
        (__attribute__((address_space(3))) unsigned int*)(lds),
        16, 0, 0);
}

// ---------------------------------------------------------------------------
// x (B,C,H,W) fp32 -> xf32[n][c] and xbf[n][c] (bf16), n = b*1024 + hw
// ---------------------------------------------------------------------------
__global__ __launch_bounds__(256) void prep_x(const float* __restrict__ x,
                                              float* __restrict__ xf32,
                                              ushort* __restrict__ xbf) {
    __shared__ float tile[32][33];
    const int b = blockIdx.x, ht = blockIdx.y, ct = blockIdx.z;
    const int t = threadIdx.x;
    const int hw0 = ht * 32, c0 = ct * 32;
    {
        const int cc = t >> 5, hh = t & 31;
        #pragma unroll
        for (int i = 0; i < 4; ++i) {
            int cl = cc + i * 8;
            tile[cl][hh] = x[((size_t)(b * 256 + c0 + cl) << 10) + hw0 + hh];
        }
    }
    __syncthreads();
    {
        const int col = t & 31, row = t >> 5;
        #pragma unroll
        for (int i = 0; i < 4; ++i) {
            int r = row + i * 8;
            float v = tile[col][r];
            size_t o = ((size_t)(b * 1024 + hw0 + r) << 8) + c0 + col;
            xf32[o] = v;
            xbf[o] = f2bf(v);
        }
    }
}

// ---------------------------------------------------------------------------
// 2 threads per code j (one per 128-half): bf16 copy + exact np pairwise S2
// ---------------------------------------------------------------------------
__global__ __launch_bounds__(256) void prep_w2(const float* __restrict__ w,
                                               ushort* __restrict__ wbf,
                                               float* __restrict__ S2a) {
#pragma clang fp contract(off)
    const int gt = blockIdx.x * 256 + threadIdx.x;
    const int j = gt >> 1, h = gt & 1;
    const float* a = w + ((size_t)j << 8) + h * 128;
    ushort* orow = wbf + ((size_t)j << 8) + h * 128;
    float r8[8];
    #pragma unroll
    for (int l = 0; l < 8; ++l) { float v = a[l]; r8[l] = v * v; }
    for (int i = 8; i < 128; i += 8) {
        #pragma unroll
        for (int l = 0; l < 8; ++l) { float v = a[i + l]; r8[l] = r8[l] + v * v; }
    }
    float hs = ((r8[0] + r8[1]) + (r8[2] + r8[3])) + ((r8[4] + r8[5]) + (r8[6] + r8[7]));
    float other = __shfl_xor(hs, 1);
    if (h == 0) S2a[j] = hs + other;   // fl(hs0 + hs1) — np order
    for (int i = 0; i < 128; i += 8) {
        ushort u8[8];
        #pragma unroll
        for (int l = 0; l < 8; ++l) u8[l] = f2bf(a[i + l]);
        *(ushort4*)(orow + i)     = make_ushort4(u8[0], u8[1], u8[2], u8[3]);
        *(ushort4*)(orow + i + 4) = make_ushort4(u8[4], u8[5], u8[6], u8[7]);
    }
}

// ---------------------------------------------------------------------------
// bf16 MFMA GEMM with CODES on M, QUERIES on N (cheap in-lane epilogue).
// global_load_lds staging, XOR-swizzled LDS layout.
// Emits per (query row, 16-code block) min approx score as fp16:
//   bm16[n][1024], 16-block id jb = blockIdx.y*8 + wr*4 + mi.
// score = S2[j] - 2 * x.w  (S1 omitted: constant per row)
// ---------------------------------------------------------------------------
__global__ __launch_bounds__(256) void gemm_min(const ushort* __restrict__ Wb,
                                                const ushort* __restrict__ Xb,
                                                const float* __restrict__ S2a,
                                                ushort* __restrict__ bm16) {
    __shared__ __attribute__((aligned(16))) ushort As[8192];  // codes  [128][64] swz
    __shared__ __attribute__((aligned(16))) ushort Bs[8192];  // queries[128][64] swz
    __shared__ __attribute__((aligned(16))) ushort stg[128 * 8];

    const int n0 = blockIdx.x * 128;   // query block
    const int j0 = blockIdx.y * 128;   // code block
    const int t  = threadIdx.x;
    const int wv = t >> 6, l = t & 63;
    const int wr = wv >> 1, wc = wv & 1;   // wr: code 64-half, wc: query 64-half
    const int q  = l >> 4, c = l & 15;

    const int lr = l >> 3;
    const int lperm = (l & 7) ^ lr;
    const size_t gA0 = ((size_t)(j0 + wv * 32 + lr) << 8) + lperm * 8;
    const size_t gB0 = ((size_t)(n0 + wv * 32 + lr) << 8) + lperm * 8;
    const int ldsbase = wv * 2048;

    floatx4 acc[4][4];
    #pragma unroll
    for (int mi = 0; mi < 4; ++mi)
        #pragma unroll
        for (int ni = 0; ni < 4; ++ni)
            acc[mi][ni] = (floatx4){0.f, 0.f, 0.f, 0.f};

    for (int kb = 0; kb < 4; ++kb) {
        if (kb) __syncthreads();
        #pragma unroll
        for (int ca = 0; ca < 4; ++ca) {
            gl_lds16(Wb + gA0 + ca * 2048 + kb * 64, As + ldsbase + ca * 512);
            gl_lds16(Xb + gB0 + ca * 2048 + kb * 64, Bs + ldsbase + ca * 512);
        }
        __syncthreads();
        #pragma unroll
        for (int kk = 0; kk < 2; ++kk) {
            short8 af[4], bf[4];
            #pragma unroll
            for (int mi = 0; mi < 4; ++mi) {
                int row = wr * 64 + mi * 16 + c;
                int pos = (kk * 4 + q) ^ (c & 7);
                af[mi] = *(const short8*)&As[row * 64 + pos * 8];
            }
            #pragma unroll
            for (int ni = 0; ni < 4; ++ni) {
                int row = wc * 64 + ni * 16 + c;
                int pos = (kk * 4 + q) ^ (c & 7);
                bf[ni] = *(const short8*)&Bs[row * 64 + pos * 8];
            }
            #pragma unroll
            for (int mi = 0; mi < 4; ++mi)
                #pragma unroll
                for (int ni = 0; ni < 4; ++ni)
                    acc[mi][ni] = __builtin_amdgcn_mfma_f32_16x16x32_bf16(
                        af[mi], bf[ni], acc[mi][ni], 0, 0, 0);
        }
    }

    // Epilogue: D rows = codes (q*4+r), cols = queries (c).
    #pragma unroll
    for (int mi = 0; mi < 4; ++mi) {
        float4 s2 = *(const float4*)&S2a[j0 + wr * 64 + mi * 16 + (q << 2)];
        #pragma unroll
        for (int ni = 0; ni < 4; ++ni) {
            float m0 = fmaf(-2.f, acc[mi][ni][0], s2.x);
            float m1 = fmaf(-2.f, acc[mi][ni][1], s2.y);
            float m2 = fmaf(-2.f, acc[mi][ni][2], s2.z);
            float m3 = fmaf(-2.f, acc[mi][ni][3], s2.w);
            float m = fminf(fminf(m0, m1), fminf(m2, m3));
            m = fminf(m, __shfl_xor(m, 16));
            m = fminf(m, __shfl_xor(m, 32));
            if (q == 0) {
                int qr = wc * 64 + ni * 16 + c;        // query row in block
                stg[qr * 8 + wr * 4 + mi] =
                    __builtin_bit_cast(ushort, (_Float16)m);
            }
        }
    }
    __syncthreads();
    if (t < 128) {
        uint4 v = *(const uint4*)&stg[t * 8];
        *(uint4*)(bm16 + ((size_t)(n0 + t) << 10) + blockIdx.y * 8) = v;
    }
}

// ---------------------------------------------------------------------------
// ONE WAVE PER ROW. One candidate code per lane; each lane's w-row is loaded
// in 4 rounds of 16 EXPLICIT independent float4 loads into registers (forces
// MLP~16; the R7 version compiled to MLP~1 at VGPR_Count=32), then the exact
// np-fp32 sequential k-order FMA dot runs from registers + x float4 LDS
// broadcasts. First-index tie-break via u64 key. Loss fused.
// ---------------------------------------------------------------------------
__global__ __launch_bounds__(256) void rescore5(const ushort* __restrict__ bm16,
                                                const float* __restrict__ xf32,
                                                const float* __restrict__ w,
                                                const float* __restrict__ S2a,
                                                int* __restrict__ idxb,
                                                float* __restrict__ xcode,
                                                float* __restrict__ loss) {
#pragma clang fp contract(off)
    __shared__ float xs[4][256];
    __shared__ short list[4][128];
    __shared__ int ncand[4];

    const int t = threadIdx.x, wv = t >> 6, l = t & 63;
    const int n = blockIdx.x * 4 + wv;
    if (l == 0) ncand[wv] = 0;

    // stage xrow (coalesced float4/lane)
    const float4 xv = *(const float4*)&xf32[((size_t)n << 8) + l * 4];
    *(float4*)&xs[wv][l * 4] = xv;

    // bm16 row: lane l covers blocks l*16 .. l*16+15 (32 B/lane, coalesced)
    const uint4* bp = (const uint4*)(bm16 + ((size_t)n << 10) + l * 16);
    const uint4 b0 = bp[0], b1 = bp[1];
    float vals[16];
    {
        unsigned uu[8] = {b0.x, b0.y, b0.z, b0.w, b1.x, b1.y, b1.z, b1.w};
        #pragma unroll
        for (int i = 0; i < 8; ++i) {
            half2v h = __builtin_bit_cast(half2v, uu[i]);
            vals[2 * i]     = (float)h[0];
            vals[2 * i + 1] = (float)h[1];
        }
    }
    float vmin = vals[0];
    #pragma unroll
    for (int i = 1; i < 16; ++i) vmin = fminf(vmin, vals[i]);
    #pragma unroll
    for (int off = 1; off <= 32; off <<= 1) vmin = fminf(vmin, __shfl_xor(vmin, off));
    const float thr = vmin + MARGINF;
    #pragma unroll
    for (int i = 0; i < 16; ++i)
        if (vals[i] <= thr) {
            int p = atomicAdd(&ncand[wv], 1);
            if (p < 128) list[wv][p] = (short)(l * 16 + i);
        }

    // exact np pairwise S1: lanes 0..15 (half h = l>>3, accumulator a = l&7)
    float racc = 0.f;
    if (l < 16) {
        const float* a_ = &xs[wv][(l >> 3) * 128];
        const int ai = l & 7;
        float v = a_[ai];
        racc = v * v;
        for (int i = 8; i < 128; i += 8) { v = a_[i + ai]; racc = racc + v * v; }
    }
    // butterfly reproduces ((r0+r1)+(r2+r3))+((r4+r5)+(r6+r7)), then hs0+hs1
    racc = racc + __shfl_xor(racc, 1);
    racc = racc + __shfl_xor(racc, 2);
    racc = racc + __shfl_xor(racc, 4);
    racc = racc + __shfl_xor(racc, 8);   // lane 0: hs0 + hs1 (np order)
    const float S1n = __shfl(racc, 0);

    // one candidate code per lane, register-batched w loads (MLP ~16)
    const int ntot = (ncand[wv] < 128 ? ncand[wv] : 128) * 16;
    unsigned long long best = ~0ull;
    for (int s = l; s < ntot; s += 64) {
        const int j = (int)list[wv][s >> 4] * 16 + (s & 15);
        const float4* wr4 = (const float4*)(w + ((size_t)j << 8));
        float g = 0.f;
        #pragma unroll
        for (int half = 0; half < 4; ++half) {
            float4 buf[16];
            #pragma unroll
            for (int i = 0; i < 16; ++i) buf[i] = wr4[half * 16 + i];  // 16 indep loads
            #pragma unroll
            for (int i = 0; i < 16; ++i) {   // sequential FMA in k-order (BLAS)
                const float4 xv4 = *(const float4*)&xs[wv][half * 64 + i * 4];
                g = fmaf(xv4.x, buf[i].x, g);
                g = fmaf(xv4.y, buf[i].y, g);
                g = fmaf(xv4.z, buf[i].z, g);
                g = fmaf(xv4.w, buf[i].w, g);
            }
        }
        float d = (S1n + S2a[j]) - 2.0f * g;
        unsigned long long key = ((unsigned long long)fsort(d) << 32) | (unsigned)j;
        if (key < best) best = key;
    }
    #pragma unroll
    for (int off = 1; off <= 32; off <<= 1) {
        unsigned long long o = __shfl_xor(best, off);
        if (o < best) best = o;
    }
    const int J = (int)(best & 0xffffffffu);
    if (l == 0) {
        idxb[n] = J;
        xcode[n] = (float)J;
    }
    // loss contribution for this row (w[J] is L2-hot)
    const float4 wj = *(const float4*)&w[((size_t)J << 8) + l * 4];
    float d0 = wj.x - xv.x, d1 = wj.y - xv.y, d2 = wj.z - xv.z, d3 = wj.w - xv.w;
    float lacc = (d0 * d0 + d1 * d1) + (d2 * d2 + d3 * d3);
    #pragma unroll
    for (int off = 1; off <= 32; off <<= 1) lacc += __shfl_xor(lacc, off);
    if (l == 0) atomicAdd(loss, lacc * (1.25f / 2097152.0f));
}

// ---------------------------------------------------------------------------
// xq_img gather (loss handled in rescore5)
// ---------------------------------------------------------------------------
__global__ __launch_bounds__(256) void outputs_k(const float* __restrict__ w,
                                                 const int* __restrict__ idxb,
                                                 float* __restrict__ out) {
    const int b = blockIdx.x, hq = blockIdx.y, cs = blockIdx.z;
    const int t = threadIdx.x;
    const int hw = hq * 256 + t;
    const int n = (b << 10) + hw;
    const int id = idxb[n];
    #pragma unroll 4
    for (int ci = 0; ci < 32; ++ci) {
        const int c_ = cs * 32 + ci;
        const size_t oo = ((size_t)((b << 8) + c_) << 10) + hw;
        out[oo] = w[((size_t)id << 8) + c_];
    }
}

// ---------------------------------------------------------------------------
extern "C" void kernel_launch(void* const* d_in, const int* in_sizes, int n_in,
                              void* d_out, int out_size, void* d_ws, size_t ws_size,
                              hipStream_t stream) {
    const float* x = (const float*)d_in[0];
    const float* w = (const float*)d_in[1];
    float* out = (float*)d_out;

    char* ws = (char*)d_ws;
    const size_t MB = 1024u * 1024u;
    ushort* xbf   = (ushort*)(ws);                   //  4 MiB
    float*  xf32  = (float*) (ws + 4 * MB);          //  8 MiB
    ushort* wbf   = (ushort*)(ws + 12 * MB);         //  8 MiB
    float*  S2a   = (float*) (ws + 20 * MB);         // 64 KiB
    ushort* bm16  = (ushort*)(ws + 21 * MB);         // 16 MiB
    int*    idxb  = (int*)   (ws + 37 * MB);         // 32 KiB

    float* loss_ptr  = out + 2097152;
    float* xcode_ptr = out + 2097153;

    hipMemsetAsync((void*)loss_ptr, 0, 4, stream);

    prep_x  <<<dim3(8, 32, 8), 256, 0, stream>>>(x, xf32, xbf);
    prep_w2 <<<dim3(128),      256, 0, stream>>>(w, wbf, S2a);
    gemm_min<<<dim3(64, 128),  256, 0, stream>>>(wbf, xbf, S2a, bm16);
    rescore5<<<dim3(2048),     256, 0, stream>>>(bm16, xf32, w, S2a, idxb,
                                                 xcode_ptr, loss_ptr);
    outputs_k<<<dim3(8, 4, 8), 256, 0, stream>>>(w, idxb, out);
}

// Round 9
// 268.541 us; speedup vs baseline: 1.1560x; 1.1362x over previous
//
#include <hip/hip_runtime.h>
#include <stdint.h>

#define NROW    8192
#define CDIM    256
#define NCODE   16384
#define MARGINF 6.0e-5f

typedef short short8 __attribute__((ext_vector_type(8)));
typedef float floatx4 __attribute__((ext_vector_type(4)));
typedef _Float16 half2v __attribute__((ext_vector_type(2)));

__device__ inline ushort f2bf(float f) {
    unsigned u = __builtin_bit_cast(unsigned, f);
    unsigned r = (u + 0x7fffu + ((u >> 16) & 1u)) >> 16;
    return (ushort)r;
}
__device__ inline unsigned fsort(float v) {
    unsigned u = __builtin_bit_cast(unsigned, v);
    return (u >> 31) ? ~u : (u | 0x80000000u);
}

__device__ inline void gl_lds16(const ushort* g, ushort* lds) {
    __builtin_amdgcn_global_load_lds(
        (const __attribute__((address_space(1))) unsigned int*)(g),
        (__attribute__((address_space(3))) unsigned int*)(lds),
        16, 0, 0);
}

// ---------------------------------------------------------------------------
// x (B,C,H,W) fp32 -> xf32[n][c] and xbf[n][c] (bf16), n = b*1024 + hw
// ---------------------------------------------------------------------------
__global__ __launch_bounds__(256) void prep_x(const float* __restrict__ x,
                                              float* __restrict__ xf32,
                                              ushort* __restrict__ xbf) {
    __shared__ float tile[32][33];
    const int b = blockIdx.x, ht = blockIdx.y, ct = blockIdx.z;
    const int t = threadIdx.x;
    const int hw0 = ht * 32, c0 = ct * 32;
    {
        const int cc = t >> 5, hh = t & 31;
        #pragma unroll
        for (int i = 0; i < 4; ++i) {
            int cl = cc + i * 8;
            tile[cl][hh] = x[((size_t)(b * 256 + c0 + cl) << 10) + hw0 + hh];
        }
    }
    __syncthreads();
    {
        const int col = t & 31, row = t >> 5;
        #pragma unroll
        for (int i = 0; i < 4; ++i) {
            int r = row + i * 8;
            float v = tile[col][r];
            size_t o = ((size_t)(b * 1024 + hw0 + r) << 8) + c0 + col;
            xf32[o] = v;
            xbf[o] = f2bf(v);
        }
    }
}

// ---------------------------------------------------------------------------
// 2 threads per code j (one per 128-half): bf16 copy + exact np pairwise S2
// ---------------------------------------------------------------------------
__global__ __launch_bounds__(256) void prep_w2(const float* __restrict__ w,
                                               ushort* __restrict__ wbf,
                                               float* __restrict__ S2a) {
#pragma clang fp contract(off)
    const int gt = blockIdx.x * 256 + threadIdx.x;
    const int j = gt >> 1, h = gt & 1;
    const float* a = w + ((size_t)j << 8) + h * 128;
    ushort* orow = wbf + ((size_t)j << 8) + h * 128;
    float r8[8];
    #pragma unroll
    for (int l = 0; l < 8; ++l) { float v = a[l]; r8[l] = v * v; }
    for (int i = 8; i < 128; i += 8) {
        #pragma unroll
        for (int l = 0; l < 8; ++l) { float v = a[i + l]; r8[l] = r8[l] + v * v; }
    }
    float hs = ((r8[0] + r8[1]) + (r8[2] + r8[3])) + ((r8[4] + r8[5]) + (r8[6] + r8[7]));
    float other = __shfl_xor(hs, 1);
    if (h == 0) S2a[j] = hs + other;   // fl(hs0 + hs1) — np order
    for (int i = 0; i < 128; i += 8) {
        ushort u8[8];
        #pragma unroll
        for (int l = 0; l < 8; ++l) u8[l] = f2bf(a[i + l]);
        *(ushort4*)(orow + i)     = make_ushort4(u8[0], u8[1], u8[2], u8[3]);
        *(ushort4*)(orow + i + 4) = make_ushort4(u8[4], u8[5], u8[6], u8[7]);
    }
}

// ---------------------------------------------------------------------------
// bf16 MFMA GEMM with CODES on M, QUERIES on N (cheap in-lane epilogue).
// global_load_lds staging, XOR-swizzled LDS layout.
// Emits per (query row, 16-code block) min approx score as fp16:
//   bm16[n][1024], 16-block id jb = blockIdx.y*8 + wr*4 + mi.
// score = S2[j] - 2 * x.w  (S1 omitted: constant per row)
// ---------------------------------------------------------------------------
__global__ __launch_bounds__(256) void gemm_min(const ushort* __restrict__ Wb,
                                                const ushort* __restrict__ Xb,
                                                const float* __restrict__ S2a,
                                                ushort* __restrict__ bm16) {
    __shared__ __attribute__((aligned(16))) ushort As[8192];  // codes  [128][64] swz
    __shared__ __attribute__((aligned(16))) ushort Bs[8192];  // queries[128][64] swz
    __shared__ __attribute__((aligned(16))) ushort stg[128 * 8];

    const int n0 = blockIdx.x * 128;   // query block
    const int j0 = blockIdx.y * 128;   // code block
    const int t  = threadIdx.x;
    const int wv = t >> 6, l = t & 63;
    const int wr = wv >> 1, wc = wv & 1;   // wr: code 64-half, wc: query 64-half
    const int q  = l >> 4, c = l & 15;

    const int lr = l >> 3;
    const int lperm = (l & 7) ^ lr;
    const size_t gA0 = ((size_t)(j0 + wv * 32 + lr) << 8) + lperm * 8;
    const size_t gB0 = ((size_t)(n0 + wv * 32 + lr) << 8) + lperm * 8;
    const int ldsbase = wv * 2048;

    floatx4 acc[4][4];
    #pragma unroll
    for (int mi = 0; mi < 4; ++mi)
        #pragma unroll
        for (int ni = 0; ni < 4; ++ni)
            acc[mi][ni] = (floatx4){0.f, 0.f, 0.f, 0.f};

    for (int kb = 0; kb < 4; ++kb) {
        if (kb) __syncthreads();
        #pragma unroll
        for (int ca = 0; ca < 4; ++ca) {
            gl_lds16(Wb + gA0 + ca * 2048 + kb * 64, As + ldsbase + ca * 512);
            gl_lds16(Xb + gB0 + ca * 2048 + kb * 64, Bs + ldsbase + ca * 512);
        }
        __syncthreads();
        #pragma unroll
        for (int kk = 0; kk < 2; ++kk) {
            short8 af[4], bf[4];
            #pragma unroll
            for (int mi = 0; mi < 4; ++mi) {
                int row = wr * 64 + mi * 16 + c;
                int pos = (kk * 4 + q) ^ (c & 7);
                af[mi] = *(const short8*)&As[row * 64 + pos * 8];
            }
            #pragma unroll
            for (int ni = 0; ni < 4; ++ni) {
                int row = wc * 64 + ni * 16 + c;
                int pos = (kk * 4 + q) ^ (c & 7);
                bf[ni] = *(const short8*)&Bs[row * 64 + pos * 8];
            }
            #pragma unroll
            for (int mi = 0; mi < 4; ++mi)
                #pragma unroll
                for (int ni = 0; ni < 4; ++ni)
                    acc[mi][ni] = __builtin_amdgcn_mfma_f32_16x16x32_bf16(
                        af[mi], bf[ni], acc[mi][ni], 0, 0, 0);
        }
    }

    // Epilogue: D rows = codes (q*4+r), cols = queries (c).
    #pragma unroll
    for (int mi = 0; mi < 4; ++mi) {
        float4 s2 = *(const float4*)&S2a[j0 + wr * 64 + mi * 16 + (q << 2)];
        #pragma unroll
        for (int ni = 0; ni < 4; ++ni) {
            float m0 = fmaf(-2.f, acc[mi][ni][0], s2.x);
            float m1 = fmaf(-2.f, acc[mi][ni][1], s2.y);
            float m2 = fmaf(-2.f, acc[mi][ni][2], s2.z);
            float m3 = fmaf(-2.f, acc[mi][ni][3], s2.w);
            float m = fminf(fminf(m0, m1), fminf(m2, m3));
            m = fminf(m, __shfl_xor(m, 16));
            m = fminf(m, __shfl_xor(m, 32));
            if (q == 0) {
                int qr = wc * 64 + ni * 16 + c;        // query row in block
                stg[qr * 8 + wr * 4 + mi] =
                    __builtin_bit_cast(ushort, (_Float16)m);
            }
        }
    }
    __syncthreads();
    if (t < 128) {
        uint4 v = *(const uint4*)&stg[t * 8];
        *(uint4*)(bm16 + ((size_t)(n0 + t) << 10) + blockIdx.y * 8) = v;
    }
}

// ---------------------------------------------------------------------------
// ONE WAVE PER ROW. One candidate code per lane; register-batched w loads
// (MLP ~16); exact np-fp32 sequential k-order FMA dot. First-index tie-break
// via u64 key. Row loss partial written NON-ATOMICALLY to lpart[n] — the
// former single-address atomicAdd serialized 8192 ops (~125 us drain).
// ---------------------------------------------------------------------------
__global__ __launch_bounds__(256) void rescore5(const ushort* __restrict__ bm16,
                                                const float* __restrict__ xf32,
                                                const float* __restrict__ w,
                                                const float* __restrict__ S2a,
                                                int* __restrict__ idxb,
                                                float* __restrict__ xcode,
                                                float* __restrict__ lpart) {
#pragma clang fp contract(off)
    __shared__ float xs[4][256];
    __shared__ short list[4][128];
    __shared__ int ncand[4];

    const int t = threadIdx.x, wv = t >> 6, l = t & 63;
    const int n = blockIdx.x * 4 + wv;
    if (l == 0) ncand[wv] = 0;

    // stage xrow (coalesced float4/lane)
    const float4 xv = *(const float4*)&xf32[((size_t)n << 8) + l * 4];
    *(float4*)&xs[wv][l * 4] = xv;

    // bm16 row: lane l covers blocks l*16 .. l*16+15 (32 B/lane, coalesced)
    const uint4* bp = (const uint4*)(bm16 + ((size_t)n << 10) + l * 16);
    const uint4 b0 = bp[0], b1 = bp[1];
    float vals[16];
    {
        unsigned uu[8] = {b0.x, b0.y, b0.z, b0.w, b1.x, b1.y, b1.z, b1.w};
        #pragma unroll
        for (int i = 0; i < 8; ++i) {
            half2v h = __builtin_bit_cast(half2v, uu[i]);
            vals[2 * i]     = (float)h[0];
            vals[2 * i + 1] = (float)h[1];
        }
    }
    float vmin = vals[0];
    #pragma unroll
    for (int i = 1; i < 16; ++i) vmin = fminf(vmin, vals[i]);
    #pragma unroll
    for (int off = 1; off <= 32; off <<= 1) vmin = fminf(vmin, __shfl_xor(vmin, off));
    const float thr = vmin + MARGINF;
    #pragma unroll
    for (int i = 0; i < 16; ++i)
        if (vals[i] <= thr) {
            int p = atomicAdd(&ncand[wv], 1);
            if (p < 128) list[wv][p] = (short)(l * 16 + i);
        }

    // exact np pairwise S1: lanes 0..15 (half h = l>>3, accumulator a = l&7)
    float racc = 0.f;
    if (l < 16) {
        const float* a_ = &xs[wv][(l >> 3) * 128];
        const int ai = l & 7;
        float v = a_[ai];
        racc = v * v;
        for (int i = 8; i < 128; i += 8) { v = a_[i + ai]; racc = racc + v * v; }
    }
    // butterfly reproduces ((r0+r1)+(r2+r3))+((r4+r5)+(r6+r7)), then hs0+hs1
    racc = racc + __shfl_xor(racc, 1);
    racc = racc + __shfl_xor(racc, 2);
    racc = racc + __shfl_xor(racc, 4);
    racc = racc + __shfl_xor(racc, 8);   // lane 0: hs0 + hs1 (np order)
    const float S1n = __shfl(racc, 0);

    // one candidate code per lane, register-batched w loads (MLP ~16)
    const int ntot = (ncand[wv] < 128 ? ncand[wv] : 128) * 16;
    unsigned long long best = ~0ull;
    for (int s = l; s < ntot; s += 64) {
        const int j = (int)list[wv][s >> 4] * 16 + (s & 15);
        const float4* wr4 = (const float4*)(w + ((size_t)j << 8));
        float g = 0.f;
        #pragma unroll
        for (int half = 0; half < 4; ++half) {
            float4 buf[16];
            #pragma unroll
            for (int i = 0; i < 16; ++i) buf[i] = wr4[half * 16 + i];  // 16 indep loads
            #pragma unroll
            for (int i = 0; i < 16; ++i) {   // sequential FMA in k-order (BLAS)
                const float4 xv4 = *(const float4*)&xs[wv][half * 64 + i * 4];
                g = fmaf(xv4.x, buf[i].x, g);
                g = fmaf(xv4.y, buf[i].y, g);
                g = fmaf(xv4.z, buf[i].z, g);
                g = fmaf(xv4.w, buf[i].w, g);
            }
        }
        float d = (S1n + S2a[j]) - 2.0f * g;
        unsigned long long key = ((unsigned long long)fsort(d) << 32) | (unsigned)j;
        if (key < best) best = key;
    }
    #pragma unroll
    for (int off = 1; off <= 32; off <<= 1) {
        unsigned long long o = __shfl_xor(best, off);
        if (o < best) best = o;
    }
    const int J = (int)(best & 0xffffffffu);
    // loss partial for this row (w[J] is L2-hot) — no atomics
    const float4 wj = *(const float4*)&w[((size_t)J << 8) + l * 4];
    float d0 = wj.x - xv.x, d1 = wj.y - xv.y, d2 = wj.z - xv.z, d3 = wj.w - xv.w;
    float lacc = (d0 * d0 + d1 * d1) + (d2 * d2 + d3 * d3);
    #pragma unroll
    for (int off = 1; off <= 32; off <<= 1) lacc += __shfl_xor(lacc, off);
    if (l == 0) {
        idxb[n] = J;
        xcode[n] = (float)J;
        lpart[n] = lacc;
    }
}

// ---------------------------------------------------------------------------
// Deterministic loss reduction: 8192 partials -> scalar
// ---------------------------------------------------------------------------
__global__ __launch_bounds__(256) void loss_fin(const float* __restrict__ lpart,
                                                float* __restrict__ loss) {
    __shared__ float red[256];
    const int t = threadIdx.x;
    float s = 0.f;
    for (int i = 0; i < 32; ++i) s += lpart[t + (i << 8)];
    red[t] = s;
    __syncthreads();
    for (int k = 128; k > 0; k >>= 1) {
        if (t < k) red[t] += red[t + k];
        __syncthreads();
    }
    if (t == 0) *loss = red[0] * (1.25f / 2097152.0f);
}

// ---------------------------------------------------------------------------
// xq_img gather
// ---------------------------------------------------------------------------
__global__ __launch_bounds__(256) void outputs_k(const float* __restrict__ w,
                                                 const int* __restrict__ idxb,
                                                 float* __restrict__ out) {
    const int b = blockIdx.x, hq = blockIdx.y, cs = blockIdx.z;
    const int t = threadIdx.x;
    const int hw = hq * 256 + t;
    const int n = (b << 10) + hw;
    const int id = idxb[n];
    #pragma unroll 4
    for (int ci = 0; ci < 32; ++ci) {
        const int c_ = cs * 32 + ci;
        const size_t oo = ((size_t)((b << 8) + c_) << 10) + hw;
        out[oo] = w[((size_t)id << 8) + c_];
    }
}

// ---------------------------------------------------------------------------
extern "C" void kernel_launch(void* const* d_in, const int* in_sizes, int n_in,
                              void* d_out, int out_size, void* d_ws, size_t ws_size,
                              hipStream_t stream) {
    const float* x = (const float*)d_in[0];
    const float* w = (const float*)d_in[1];
    float* out = (float*)d_out;

    char* ws = (char*)d_ws;
    const size_t MB = 1024u * 1024u;
    ushort* xbf   = (ushort*)(ws);                   //  4 MiB
    float*  xf32  = (float*) (ws + 4 * MB);          //  8 MiB
    ushort* wbf   = (ushort*)(ws + 12 * MB);         //  8 MiB
    float*  S2a   = (float*) (ws + 20 * MB);         // 64 KiB
    ushort* bm16  = (ushort*)(ws + 21 * MB);         // 16 MiB
    int*    idxb  = (int*)   (ws + 37 * MB);         // 32 KiB
    float*  lpart = (float*) (ws + 37 * MB + 65536); // 32 KiB

    float* loss_ptr  = out + 2097152;
    float* xcode_ptr = out + 2097153;

    prep_x  <<<dim3(8, 32, 8), 256, 0, stream>>>(x, xf32, xbf);
    prep_w2 <<<dim3(128),      256, 0, stream>>>(w, wbf, S2a);
    gemm_min<<<dim3(64, 128),  256, 0, stream>>>(wbf, xbf, S2a, bm16);
    rescore5<<<dim3(2048),     256, 0, stream>>>(bm16, xf32, w, S2a, idxb,
                                                 xcode_ptr, lpart);
    loss_fin<<<dim3(1),        256, 0, stream>>>(lpart, loss_ptr);
    outputs_k<<<dim3(8, 4, 8), 256, 0, stream>>>(w, idxb, out);
}